// Round 1
// baseline (425.782 us; speedup 1.0000x reference)
//
#include <hip/hip_runtime.h>

#define BB 512
#define TT 512
#define KK 64

// ---------------------------------------------------------------------------
// Kernel 1: seq_lens[b] = int(mean_k(sum_t(sign(abs(x)))))  == nonzero_count >> 6
// (counts are integers <= 32768, fp32-exact in the reference; >>6 == trunc(mean))
// ---------------------------------------------------------------------------
__global__ __launch_bounds__(256) void seqlen_kernel(const float* __restrict__ inp,
                                                     int* __restrict__ seq_lens) {
    int b = blockIdx.x;
    int tid = threadIdx.x;
    const float4* p4 = (const float4*)(inp + (size_t)b * TT * KK);
    const int n4 = TT * KK / 4;  // 8192
    int cnt = 0;
    for (int idx = tid; idx < n4; idx += 256) {
        float4 v = p4[idx];
        cnt += (v.x != 0.0f) + (v.y != 0.0f) + (v.z != 0.0f) + (v.w != 0.0f);
    }
    #pragma unroll
    for (int off = 32; off > 0; off >>= 1) cnt += __shfl_down(cnt, off, 64);
    __shared__ int wsum[4];
    if ((tid & 63) == 0) wsum[tid >> 6] = cnt;
    __syncthreads();
    if (tid == 0) seq_lens[b] = (wsum[0] + wsum[1] + wsum[2] + wsum[3]) >> 6;
}

// ---------------------------------------------------------------------------
// Kernel 2: Viterbi forward + backtrace. One wave (64 lanes) per batch.
// lane j = to-tag. alpha[i] broadcast via v_readlane. bp kept in LDS (32 KB).
// Argmax ties: first occurrence (strict >, ascending i, contiguous chunks).
// ---------------------------------------------------------------------------
__global__ __launch_bounds__(64) void viterbi_kernel(const float* __restrict__ pot,
                                                     const float* __restrict__ trans,
                                                     const int* __restrict__ seq_lens,
                                                     int* __restrict__ out) {
    __shared__ unsigned char bp[TT][KK];  // bp[t][j], valid for t >= 1 (32 KB)

    const int b = blockIdx.x;
    const int j = threadIdx.x;  // 0..63

    // trans column j in registers: tc[i] = trans[i][j] (coalesced across lanes)
    float tc[KK];
    #pragma unroll
    for (int i = 0; i < KK; ++i) tc[i] = trans[i * KK + j];

    const float* pb = pot + (size_t)b * TT * KK;
    float alpha = pb[j];
    const int seqlen = seq_lens[b];

    for (int t = 1; t < TT; ++t) {
        float ptj = pb[t * KK + j];  // issued early, latency hidden under VALU

        // max/argmax over i in 4 contiguous chunks of 16 (ILP), strict-> ties
        float m[4];
        int am[4];
        #pragma unroll
        for (int c = 0; c < 4; ++c) {
            const int i = c * 16;
            float ai = __int_as_float(__builtin_amdgcn_readlane(__float_as_int(alpha), i));
            m[c] = ai + tc[i];
            am[c] = i;
        }
        #pragma unroll
        for (int q = 1; q < 16; ++q) {
            #pragma unroll
            for (int c = 0; c < 4; ++c) {
                const int i = c * 16 + q;
                float ai = __int_as_float(__builtin_amdgcn_readlane(__float_as_int(alpha), i));
                float s = ai + tc[i];
                bool g = s > m[c];           // strict: keeps first max in chunk
                m[c] = g ? s : m[c];
                am[c] = g ? i : am[c];
            }
        }
        float M = m[0];
        int BI = am[0];
        #pragma unroll
        for (int c = 1; c < 4; ++c) {
            bool g = m[c] > M;               // strict: earlier chunk wins ties
            M = g ? m[c] : M;
            BI = g ? am[c] : BI;
        }

        const bool valid = (t < seqlen);     // wave-uniform
        float na = ptj + M;
        alpha = valid ? na : alpha;          // freeze past seq end
        bp[t][j] = (unsigned char)(valid ? BI : j);  // identity bp past end
    }

    // wave argmax over final alpha (first occurrence on ties)
    float v = alpha;
    int idx = j;
    #pragma unroll
    for (int off = 1; off < 64; off <<= 1) {
        float vo = __shfl_xor(v, off, 64);
        int io = __shfl_xor(idx, off, 64);
        bool take = (vo > v) || (vo == v && io < idx);
        v = take ? vo : v;
        idx = take ? io : idx;
    }
    const int last_tag = idx;  // identical in all lanes

    __syncthreads();  // make bp LDS writes visible (cheap: single wave)

    if (j == 0) {
        int* ob = out + b * TT;
        int cur = last_tag;
        ob[TT - 1] = cur;
        for (int p = TT - 2; p >= 0; --p) {
            cur = bp[p + 1][cur];
            ob[p] = cur;
        }
    }
}

extern "C" void kernel_launch(void* const* d_in, const int* in_sizes, int n_in,
                              void* d_out, int out_size, void* d_ws, size_t ws_size,
                              hipStream_t stream) {
    const float* inp = (const float*)d_in[0];     // [B, T, K] fp32
    const float* trans = (const float*)d_in[1];   // [K, K] fp32
    int* out = (int*)d_out;                       // [B, T] int32
    int* seq_lens = (int*)d_ws;                   // 512 * 4 B scratch

    seqlen_kernel<<<BB, 256, 0, stream>>>(inp, seq_lens);
    viterbi_kernel<<<BB, KK, 0, stream>>>(inp, trans, seq_lens, out);
}

// Round 2
// 395.735 us; speedup vs baseline: 1.0759x; 1.0759x over previous
//
#include <hip/hip_runtime.h>

#define BB 512
#define TT 512
#define KK 64
#define WPB 4
#define IPW (KK / WPB)   // 16 from-tags per wave

// ---------------------------------------------------------------------------
// Kernel 1: partial nonzero counts. Block (b, quarter): counts nonzeros in
// one quarter of batch b's [T,K] slab -> partials[b*4+q]. (seq_len = sum>>6,
// exact: counts are integers <= 32768, fp32-exact in the reference.)
// ---------------------------------------------------------------------------
__global__ __launch_bounds__(256) void count_kernel(const float* __restrict__ inp,
                                                    int* __restrict__ partials) {
    const int blk = blockIdx.x;        // 0..2047
    const int b = blk >> 2, q = blk & 3;
    const int tid = threadIdx.x;
    const float4* p4 = (const float4*)(inp + (size_t)b * TT * KK + (size_t)q * (TT * KK / 4));
    int cnt = 0;
    #pragma unroll
    for (int r = 0; r < 8; ++r) {      // 256 threads * 8 * float4 = 8192 floats
        float4 v = p4[tid + 256 * r];
        cnt += (v.x != 0.f) + (v.y != 0.f) + (v.z != 0.f) + (v.w != 0.f);
    }
    #pragma unroll
    for (int off = 32; off > 0; off >>= 1) cnt += __shfl_down(cnt, off, 64);
    __shared__ int wsum[4];
    if ((tid & 63) == 0) wsum[tid >> 6] = cnt;
    __syncthreads();
    if (tid == 0) partials[blk] = wsum[0] + wsum[1] + wsum[2] + wsum[3];
}

// ---------------------------------------------------------------------------
// Kernel 2: Viterbi forward + backtrace. 4 waves per batch; wave w reduces
// from-tags i in [w*16, w*16+16); partial (max, argmax) exchanged through
// double-buffered LDS each step. Tie semantics = first occurrence (strict >,
// ascending i everywhere, merge trees ordered lower-i-first).
// ---------------------------------------------------------------------------
__global__ __launch_bounds__(256) void viterbi_kernel(const float* __restrict__ pot,
                                                      const float* __restrict__ trans,
                                                      const int* __restrict__ partials,
                                                      int* __restrict__ out) {
    __shared__ unsigned char bp[TT][KK];   // 32 KB backpointers
    __shared__ int2 ex[2][WPB][KK];        // 4 KB partial (m bits, argmax), double-buffered

    const int b = blockIdx.x;
    const int lane = threadIdx.x & 63;     // j = to-tag
    const int w = threadIdx.x >> 6;        // wave id = i-range
    const int i0 = w * IPW;

    // trans column j for this wave's i-range (coalesced across lanes)
    float tc[IPW];
    #pragma unroll
    for (int q = 0; q < IPW; ++q) tc[q] = trans[(i0 + q) * KK + lane];

    const int seqlen = (partials[b * 4 + 0] + partials[b * 4 + 1] +
                        partials[b * 4 + 2] + partials[b * 4 + 3]) >> 6;

    const float* pb = pot + (size_t)b * TT * KK;
    float alpha = pb[lane];                // all waves hold the full alpha vector
    float pnext = pb[KK + lane];           // prefetch t=1

    for (int t = 1; t < TT; ++t) {
        const float ptj = pnext;
        {   // prefetch next step's potentials (clamped, uniform select)
            const int tn = (t + 1 < TT) ? (t + 1) : (TT - 1);
            pnext = pb[tn * KK + lane];
        }

        // 4 chunks of 4 for ILP; strict > keeps first occurrence within chunk
        float m[4]; int am[4];
        #pragma unroll
        for (int c = 0; c < 4; ++c) {
            const int base = i0 + c * 4;
            float ai = __int_as_float(__builtin_amdgcn_readlane(__float_as_int(alpha), base));
            m[c] = ai + tc[c * 4];
            am[c] = base;
            #pragma unroll
            for (int qq = 1; qq < 4; ++qq) {
                const int iq = base + qq;
                float aq = __int_as_float(__builtin_amdgcn_readlane(__float_as_int(alpha), iq));
                float s = aq + tc[c * 4 + qq];
                bool g = s > m[c];
                m[c] = g ? s : m[c];
                am[c] = g ? iq : am[c];
            }
        }
        // tree merge, lower-i chunk wins ties (strict > on higher chunk)
        bool g01 = m[1] > m[0]; float m01 = g01 ? m[1] : m[0]; int a01 = g01 ? am[1] : am[0];
        bool g23 = m[3] > m[2]; float m23 = g23 ? m[3] : m[2]; int a23 = g23 ? am[3] : am[2];
        bool gg  = m23 > m01;  float mw  = gg ? m23 : m01;    int aw  = gg ? a23 : a01;

        const int buf = t & 1;
        ex[buf][w][lane] = make_int2(__float_as_int(mw), aw);
        __syncthreads();
        const int2 e0 = ex[buf][0][lane], e1 = ex[buf][1][lane];
        const int2 e2 = ex[buf][2][lane], e3 = ex[buf][3][lane];
        const float f0 = __int_as_float(e0.x), f1 = __int_as_float(e1.x);
        const float f2 = __int_as_float(e2.x), f3 = __int_as_float(e3.x);
        bool h01 = f1 > f0; float p01 = h01 ? f1 : f0; int q01 = h01 ? e1.y : e0.y;
        bool h23 = f3 > f2; float p23 = h23 ? f3 : f2; int q23 = h23 ? e3.y : e2.y;
        bool hh  = p23 > p01; float M = hh ? p23 : p01; int BI = hh ? q23 : q01;

        const bool valid = (t < seqlen);   // wave-uniform
        alpha = valid ? (ptj + M) : alpha; // freeze past seq end
        if (w == 0) bp[t][lane] = (unsigned char)(valid ? BI : lane);
    }

    // wave 0: final argmax (first occurrence on ties) + serial backtrace
    if (w == 0) {
        float v = alpha; int idx = lane;
        #pragma unroll
        for (int off = 1; off < 64; off <<= 1) {
            float vo = __shfl_xor(v, off, 64);
            int io  = __shfl_xor(idx, off, 64);
            bool take = (vo > v) || (vo == v && io < idx);
            v = take ? vo : v;
            idx = take ? io : idx;
        }
        if (lane == 0) {
            int* ob = out + b * TT;
            int cur = idx;
            ob[TT - 1] = cur;
            for (int p = TT - 2; p >= 0; --p) {
                cur = bp[p + 1][cur];
                ob[p] = cur;
            }
        }
    }
}

extern "C" void kernel_launch(void* const* d_in, const int* in_sizes, int n_in,
                              void* d_out, int out_size, void* d_ws, size_t ws_size,
                              hipStream_t stream) {
    const float* inp = (const float*)d_in[0];     // [B, T, K] fp32
    const float* trans = (const float*)d_in[1];   // [K, K] fp32
    int* out = (int*)d_out;                       // [B, T] int32
    int* partials = (int*)d_ws;                   // 2048 ints of scratch

    count_kernel<<<BB * 4, 256, 0, stream>>>(inp, partials);
    viterbi_kernel<<<BB, 256, 0, stream>>>(inp, trans, partials, out);
}